// Round 1
// baseline (2870.056 us; speedup 1.0000x reference)
//
#include <hip/hip_runtime.h>
#include <math.h>

#define B_   4
#define S_   512
#define D_   1024
#define H_   16
#define E_   4
#define HD_  64
#define D2_  512
#define NTOK (B_*S_)   // 2048

// ---------------------------------------------------------------------------
// Generic tiled fp32 GEMM: C[M,N] = A[M,K] @ B[K,N] + bias[N]
// If emask != nullptr (combine mode): C[m,n] += emask[m*E_+e] * (acc + bias[n])
// with early-exit when the whole 64-row tile has zero mask.
// BM=BN=64, BK=16, 256 threads, 4x4 micro-tile per thread.
// ---------------------------------------------------------------------------
__global__ __launch_bounds__(256) void gemm_bias(
    const float* __restrict__ A, const float* __restrict__ Bm,
    const float* __restrict__ bias, float* __restrict__ C,
    int M, int N, int K,
    const float* __restrict__ emask, int e)
{
    __shared__ float As[64][17];
    __shared__ float Bs[16][65];

    const int tid  = threadIdx.x;
    const int brow = blockIdx.y * 64;
    const int bcol = blockIdx.x * 64;

    if (emask) {
        __shared__ int flag;
        if (tid == 0) flag = 0;
        __syncthreads();
        bool any = false;
        for (int m = tid; m < 64; m += 256)
            if (emask[(size_t)(brow + m) * E_ + e] != 0.f) any = true;
        if (any) flag = 1;
        __syncthreads();
        if (!flag) return;
    }

    const int tr = tid >> 4;   // 0..15
    const int tc = tid & 15;   // 0..15

    float acc[4][4] = {};

    for (int k0 = 0; k0 < K; k0 += 16) {
#pragma unroll
        for (int i = 0; i < 4; i++) {
            int idx = tid + i * 256;          // 0..1023
            int m = idx >> 4, kk = idx & 15;
            As[m][kk] = A[(size_t)(brow + m) * K + k0 + kk];
        }
#pragma unroll
        for (int i = 0; i < 4; i++) {
            int idx = tid + i * 256;
            int kk = idx >> 6, n = idx & 63;
            Bs[kk][n] = Bm[(size_t)(k0 + kk) * N + bcol + n];
        }
        __syncthreads();
#pragma unroll
        for (int kk = 0; kk < 16; kk++) {
            float a[4], b[4];
#pragma unroll
            for (int i = 0; i < 4; i++) a[i] = As[tr * 4 + i][kk];
#pragma unroll
            for (int j = 0; j < 4; j++) b[j] = Bs[kk][tc * 4 + j];
#pragma unroll
            for (int i = 0; i < 4; i++)
#pragma unroll
                for (int j = 0; j < 4; j++) acc[i][j] += a[i] * b[j];
        }
        __syncthreads();
    }

#pragma unroll
    for (int i = 0; i < 4; i++) {
        int m = brow + tr * 4 + i;
#pragma unroll
        for (int j = 0; j < 4; j++) {
            int n = bcol + tc * 4 + j;
            float v = acc[i][j] + bias[n];
            if (emask) {
                float s = emask[(size_t)m * E_ + e];
                if (s != 0.f) C[(size_t)m * N + n] += s * v;
            } else {
                C[(size_t)m * N + n] = v;
            }
        }
    }
}

// ---------------------------------------------------------------------------
// Router post: per token, LayerNorm(h) -> relu -> logits = h @ Wr2 + br2
// -> softmax -> top-2 -> emask row [E_]
// One block (256 threads) per token; D2_=512 -> 2 elements/thread.
// ---------------------------------------------------------------------------
__global__ __launch_bounds__(256) void router_post(
    const float* __restrict__ h,
    const float* __restrict__ ln_g, const float* __restrict__ ln_b,
    const float* __restrict__ Wr2, const float* __restrict__ br2,
    float* __restrict__ emask)
{
    const int t = blockIdx.x;
    const int tid = threadIdx.x;
    __shared__ float red[256];
    __shared__ float logits[E_];

    const float* hr = h + (size_t)t * D2_;
    float x0 = hr[tid], x1 = hr[tid + 256];

    red[tid] = x0 + x1; __syncthreads();
    for (int off = 128; off; off >>= 1) { if (tid < off) red[tid] += red[tid + off]; __syncthreads(); }
    float mu = red[0] * (1.f / 512.f);
    __syncthreads();

    float d0 = x0 - mu, d1 = x1 - mu;
    red[tid] = d0 * d0 + d1 * d1; __syncthreads();
    for (int off = 128; off; off >>= 1) { if (tid < off) red[tid] += red[tid + off]; __syncthreads(); }
    float rs = rsqrtf(red[0] * (1.f / 512.f) + 1e-5f);
    __syncthreads();

    float n0 = fmaxf(fmaf(d0 * rs, ln_g[tid],       ln_b[tid]),       0.f);
    float n1 = fmaxf(fmaf(d1 * rs, ln_g[tid + 256], ln_b[tid + 256]), 0.f);

    for (int e = 0; e < E_; e++) {
        red[tid] = n0 * Wr2[(size_t)tid * E_ + e] + n1 * Wr2[(size_t)(tid + 256) * E_ + e];
        __syncthreads();
        for (int off = 128; off; off >>= 1) { if (tid < off) red[tid] += red[tid + off]; __syncthreads(); }
        if (tid == 0) logits[e] = red[0] + br2[e];
        __syncthreads();
    }

    if (tid == 0) {
        float mx = fmaxf(fmaxf(logits[0], logits[1]), fmaxf(logits[2], logits[3]));
        float p[E_], sum = 0.f;
        for (int e = 0; e < E_; e++) { p[e] = expf(logits[e] - mx); sum += p[e]; }
        float inv = 1.f / sum;
        for (int e = 0; e < E_; e++) p[e] *= inv;
        int i1 = 0;
        for (int e = 1; e < E_; e++) if (p[e] > p[i1]) i1 = e;
        int i2 = -1;
        for (int e = 0; e < E_; e++) { if (e == i1) continue; if (i2 < 0 || p[e] > p[i2]) i2 = e; }
        float o[E_] = {0.f, 0.f, 0.f, 0.f};
        o[i1] = p[i1]; o[i2] = p[i2];
        for (int e = 0; e < E_; e++) emask[(size_t)t * E_ + e] = o[e];
    }
}

// ---------------------------------------------------------------------------
// Flash-style fp32 attention for one expert.
// grid = (S_/32, B_*H_), 256 threads.
// Per block: 32 q-rows of one (b,h). Loop over 8 key tiles of 64.
// Thread roles: sr = tid/8 (row 0..31), sg = tid%8 (8 score cols / 8 O dims).
// ---------------------------------------------------------------------------
__global__ __launch_bounds__(256) void attn_kernel(
    const float* __restrict__ Qb, const float* __restrict__ Kb,
    const float* __restrict__ Vb, float* __restrict__ Ob)
{
    __shared__ float Qs[32][HD_ + 1];
    __shared__ float Ks[64][HD_ + 1];
    __shared__ float Vs[64][HD_ + 1];
    __shared__ float Ss[32][65];

    const int tid = threadIdx.x;
    const int bh  = blockIdx.y;
    const int b   = bh >> 4;
    const int hh  = bh & 15;
    const int q0  = blockIdx.x * 32;
    const size_t base = (size_t)b * S_ * D_ + (size_t)hh * HD_;

    // load Q tile (32x64)
#pragma unroll
    for (int i = 0; i < 8; i++) {
        int idx = tid + i * 256;
        int r = idx >> 6, d = idx & 63;
        Qs[r][d] = Qb[base + (size_t)(q0 + r) * D_ + d];
    }

    const int sr = tid >> 3;
    const int sg = tid & 7;

    float m = -1e30f, l = 0.f;
    float o[8] = {0.f, 0.f, 0.f, 0.f, 0.f, 0.f, 0.f, 0.f};

    for (int kt = 0; kt < S_ / 64; kt++) {
        const int k0 = kt * 64;
        // load K,V tiles (64x64 each)
#pragma unroll
        for (int i = 0; i < 16; i++) {
            int idx = tid + i * 256;
            int r = idx >> 6, d = idx & 63;
            Ks[r][d] = Kb[base + (size_t)(k0 + r) * D_ + d];
            Vs[r][d] = Vb[base + (size_t)(k0 + r) * D_ + d];
        }
        __syncthreads();

        // scores: this thread computes S[sr][sg*8 + j], j=0..7
        float sc[8] = {0.f, 0.f, 0.f, 0.f, 0.f, 0.f, 0.f, 0.f};
        for (int d = 0; d < HD_; d++) {
            float qv = Qs[sr][d];
#pragma unroll
            for (int j = 0; j < 8; j++) sc[j] += qv * Ks[sg * 8 + j][d];
        }
#pragma unroll
        for (int j = 0; j < 8; j++) { sc[j] *= 0.125f; Ss[sr][sg * 8 + j] = sc[j]; }
        __syncthreads();

        // row max over the 64 new scores
        float tm = -1e30f;
        for (int j = 0; j < 64; j++) tm = fmaxf(tm, Ss[sr][j]);
        float nm = fmaxf(m, tm);
        float scale = expf(m - nm);
        __syncthreads();   // all max-scans done before overwriting Ss with p

        float psum_own = 0.f;
#pragma unroll
        for (int j = 0; j < 8; j++) {
            float pj = expf(sc[j] - nm);
            Ss[sr][sg * 8 + j] = pj;
            psum_own += pj;
        }
        __syncthreads();   // p visible to whole row group

        float tl = 0.f;
        for (int j = 0; j < 64; j++) tl = tl + Ss[sr][j];
        l = scale * l + tl;

#pragma unroll
        for (int c = 0; c < 8; c++) o[c] *= scale;
        for (int j = 0; j < 64; j++) {
            float pj = Ss[sr][j];
#pragma unroll
            for (int c = 0; c < 8; c++) o[c] += pj * Vs[j][sg * 8 + c];
        }
        m = nm;
        __syncthreads();   // done reading Ks/Vs/Ss before next tile load
    }

    float inv = 1.f / l;
    size_t orow = base + (size_t)(q0 + sr) * D_ + sg * 8;
#pragma unroll
    for (int c = 0; c < 8; c++) Ob[orow + c] = o[c] * inv;
}

// ---------------------------------------------------------------------------
extern "C" void kernel_launch(void* const* d_in, const int* in_sizes, int n_in,
                              void* d_out, int out_size, void* d_ws, size_t ws_size,
                              hipStream_t stream) {
    const float* x   = (const float*)d_in[0];
    const float* Wq  = (const float*)d_in[1];
    const float* bq  = (const float*)d_in[2];
    const float* Wk  = (const float*)d_in[3];
    const float* bk  = (const float*)d_in[4];
    const float* Wv  = (const float*)d_in[5];
    const float* bv  = (const float*)d_in[6];
    const float* Wo  = (const float*)d_in[7];
    const float* bo  = (const float*)d_in[8];
    const float* Wr1 = (const float*)d_in[9];
    const float* br1 = (const float*)d_in[10];
    const float* lng = (const float*)d_in[11];
    const float* lnb = (const float*)d_in[12];
    const float* Wr2 = (const float*)d_in[13];
    const float* br2 = (const float*)d_in[14];

    float* out = (float*)d_out;
    float* ws  = (float*)d_ws;

    float* h     = ws;                               // NTOK*D2_
    float* emask = h + (size_t)NTOK * D2_;           // NTOK*E_
    float* Qb    = emask + (size_t)NTOK * E_;        // NTOK*D_
    float* Kbuf  = Qb + (size_t)NTOK * D_;
    float* Vbuf  = Kbuf + (size_t)NTOK * D_;
    float* Ob    = Vbuf + (size_t)NTOK * D_;

    hipMemsetAsync(d_out, 0, (size_t)NTOK * D_ * sizeof(float), stream);

    dim3 blk(256);

    // router hidden: h = x @ Wr1 + br1   [2048, 512]
    gemm_bias<<<dim3(D2_ / 64, NTOK / 64), blk, 0, stream>>>(
        x, Wr1, br1, h, NTOK, D2_, D_, nullptr, 0);

    // router post: LN + relu + logits + softmax + top2 -> emask
    router_post<<<dim3(NTOK), blk, 0, stream>>>(h, lng, lnb, Wr2, br2, emask);

    for (int e = 0; e < E_; e++) {
        const float* wq = Wq + (size_t)e * D_ * D_;
        const float* wk = Wk + (size_t)e * D_ * D_;
        const float* wv = Wv + (size_t)e * D_ * D_;
        const float* wo = Wo + (size_t)e * D_ * D_;

        gemm_bias<<<dim3(D_ / 64, NTOK / 64), blk, 0, stream>>>(
            x, wq, bq + (size_t)e * D_, Qb, NTOK, D_, D_, nullptr, 0);
        gemm_bias<<<dim3(D_ / 64, NTOK / 64), blk, 0, stream>>>(
            x, wk, bk + (size_t)e * D_, Kbuf, NTOK, D_, D_, nullptr, 0);
        gemm_bias<<<dim3(D_ / 64, NTOK / 64), blk, 0, stream>>>(
            x, wv, bv + (size_t)e * D_, Vbuf, NTOK, D_, D_, nullptr, 0);

        attn_kernel<<<dim3(S_ / 32, B_ * H_), blk, 0, stream>>>(Qb, Kbuf, Vbuf, Ob);

        // out += emask[:,e] * (Ob @ Wo[e] + bo[e])
        gemm_bias<<<dim3(D_ / 64, NTOK / 64), blk, 0, stream>>>(
            Ob, wo, bo + (size_t)e * D_, out, NTOK, D_, D_, emask, e);
    }
}

// Round 2
// 600.220 us; speedup vs baseline: 4.7817x; 4.7817x over previous
//
#include <hip/hip_runtime.h>
#include <hip/hip_bf16.h>
#include <math.h>

#define B_   4
#define S_   512
#define D_   1024
#define H_   16
#define E_   4
#define HD_  64
#define D2_  512
#define NTOK (B_*S_)   // 2048

typedef unsigned short ushort;
typedef short shortv8 __attribute__((ext_vector_type(8)));
typedef ushort ushortv8 __attribute__((ext_vector_type(8)));
typedef ushort ushortv4 __attribute__((ext_vector_type(4)));
typedef float floatv4 __attribute__((ext_vector_type(4)));

__device__ __forceinline__ ushort f2bf(float f) {
    union { __hip_bfloat16 b; ushort u; } cv;
    cv.b = __float2bfloat16(f);
    return cv.u;
}
__device__ __forceinline__ float bf2f(ushort u) {
    union { ushort u; __hip_bfloat16 b; } cv;
    cv.u = u;
    return __bfloat162float(cv.b);
}
__device__ __forceinline__ void splitbf(float v, ushort& hi, ushort& lo) {
    hi = f2bf(v);
    lo = f2bf(v - bf2f(hi));
}
__device__ __forceinline__ void gload16(const ushort* g, ushort* l) {
    __builtin_amdgcn_global_load_lds(
        (const __attribute__((address_space(1))) unsigned int*)g,
        (__attribute__((address_space(3))) unsigned int*)l, 16, 0, 0);
}

// ---------------------------------------------------------------------------
// Split-bf16 GEMM core: C = A @ Wt^T where A=[M][K] (hi/lo bf16),
// Wt=[N][K] (hi/lo bf16, pre-transposed weight). 128x128 tile, BK=32,
// 256 threads = 4 waves (2x2), each wave 64x64 = 4x4 fragments 16x16x32.
// 3-term split: ah*bh + ah*bl + al*bh.
// LDS: 4 tiles of 128x32 bf16 (8KB each). XOR chunk swizzle c^( (m>>1)&3 ),
// applied on global SOURCE at staging and on LDS READ (involution, rule #21).
// ---------------------------------------------------------------------------
__device__ __forceinline__ void gemm_core(
    const ushort* __restrict__ A0, const ushort* __restrict__ A1,
    const ushort* __restrict__ B0, const ushort* __restrict__ B1,
    int K, int brow, int bcol, ushort* lds, floatv4 acc[4][4])
{
    const int tid  = threadIdx.x;
    const int wave = tid >> 6, lane = tid & 63;
    const int wm = wave >> 1, wn = wave & 1;
    const int lr = lane & 15, lc = lane >> 4;

    const ushort* gsrc[4] = {A0, A1, B0, B1};
    size_t  goff[4][2];
    ushort* ldst[4][2];
#pragma unroll
    for (int t = 0; t < 4; t++) {
        int rb = (t < 2) ? brow : bcol;
#pragma unroll
        for (int s = 0; s < 2; s++) {
            int p = s * 256 + tid;
            int m = p >> 2;
            int c = (p & 3) ^ ((m >> 1) & 3);
            goff[t][s] = (size_t)(rb + m) * K + c * 8;
            ldst[t][s] = lds + t * 4096 + p * 8;
        }
    }

    int aoff[4], boff[4];
#pragma unroll
    for (int i = 0; i < 4; i++) {
        int ra = wm * 64 + i * 16 + lr;
        aoff[i] = ra * 32 + ((lc ^ ((ra >> 1) & 3)) * 8);
        int rb2 = wn * 64 + i * 16 + lr;
        boff[i] = rb2 * 32 + ((lc ^ ((rb2 >> 1) & 3)) * 8);
    }

    for (int k0 = 0; k0 < K; k0 += 32) {
        __syncthreads();
#pragma unroll
        for (int t = 0; t < 4; t++)
#pragma unroll
            for (int s = 0; s < 2; s++)
                gload16(gsrc[t] + goff[t][s] + k0, ldst[t][s]);
        __syncthreads();

        shortv8 ah[4], al[4], bh[4], bl[4];
#pragma unroll
        for (int i = 0; i < 4; i++) {
            ah[i] = *(const shortv8*)(lds +         aoff[i]);
            al[i] = *(const shortv8*)(lds +  4096 + aoff[i]);
            bh[i] = *(const shortv8*)(lds +  8192 + boff[i]);
            bl[i] = *(const shortv8*)(lds + 12288 + boff[i]);
        }
#pragma unroll
        for (int mi = 0; mi < 4; mi++)
#pragma unroll
            for (int nj = 0; nj < 4; nj++) {
                acc[mi][nj] = __builtin_amdgcn_mfma_f32_16x16x32_bf16(ah[mi], bh[nj], acc[mi][nj], 0, 0, 0);
                acc[mi][nj] = __builtin_amdgcn_mfma_f32_16x16x32_bf16(ah[mi], bl[nj], acc[mi][nj], 0, 0, 0);
                acc[mi][nj] = __builtin_amdgcn_mfma_f32_16x16x32_bf16(al[mi], bh[nj], acc[mi][nj], 0, 0, 0);
            }
    }
}

// ---- GEMM variant: fp32 output + bias (router hidden) ----
__global__ __launch_bounds__(256, 2) void gemm_f32(
    const ushort* __restrict__ A0, const ushort* __restrict__ A1,
    const ushort* __restrict__ B0, const ushort* __restrict__ B1,
    const float* __restrict__ bias, float* __restrict__ C, int N, int K)
{
    __shared__ ushort lds[16384];
    floatv4 acc[4][4];
#pragma unroll
    for (int i = 0; i < 4; i++)
#pragma unroll
        for (int j = 0; j < 4; j++)
#pragma unroll
            for (int q = 0; q < 4; q++) acc[i][j][q] = 0.f;

    const int brow = blockIdx.y * 128, bcol = blockIdx.x * 128;
    gemm_core(A0, A1, B0, B1, K, brow, bcol, lds, acc);

    const int lane = threadIdx.x & 63, wave = threadIdx.x >> 6;
    const int wm = wave >> 1, wn = wave & 1, lr = lane & 15, lc = lane >> 4;
#pragma unroll
    for (int mi = 0; mi < 4; mi++)
#pragma unroll
        for (int nj = 0; nj < 4; nj++)
#pragma unroll
            for (int i = 0; i < 4; i++) {
                int row = brow + wm * 64 + mi * 16 + lc * 4 + i;
                int col = bcol + wn * 64 + nj * 16 + lr;
                C[(size_t)row * N + col] = acc[mi][nj][i] + bias[col];
            }
}

// ---- GEMM variant: fused Q/K/V projections (z picks output), split-bf16 out ----
__global__ __launch_bounds__(256, 2) void gemm_qkv(
    const ushort* __restrict__ xh, const ushort* __restrict__ xl,
    const ushort* __restrict__ wth, const ushort* __restrict__ wtl,
    const float* __restrict__ bq, const float* __restrict__ bk, const float* __restrict__ bv,
    ushort* __restrict__ qh, ushort* __restrict__ ql,
    ushort* __restrict__ kh, ushort* __restrict__ kl,
    ushort* __restrict__ vb, int K)
{
    __shared__ ushort lds[16384];
    const int z = blockIdx.z;
    const ushort* B0 = wth + (size_t)z * D_ * D_;
    const ushort* B1 = wtl + (size_t)z * D_ * D_;
    const float* bias = (z == 0) ? bq : (z == 1) ? bk : bv;
    ushort* Oh = (z == 0) ? qh : (z == 1) ? kh : vb;
    ushort* Ol = (z == 0) ? ql : (z == 1) ? kl : nullptr;
    const float scale = (z == 0) ? 0.125f : 1.0f;   // fold 1/sqrt(HD) into Q

    floatv4 acc[4][4];
#pragma unroll
    for (int i = 0; i < 4; i++)
#pragma unroll
        for (int j = 0; j < 4; j++)
#pragma unroll
            for (int q = 0; q < 4; q++) acc[i][j][q] = 0.f;

    const int brow = blockIdx.y * 128, bcol = blockIdx.x * 128;
    gemm_core(xh, xl, B0, B1, K, brow, bcol, lds, acc);

    const int lane = threadIdx.x & 63, wave = threadIdx.x >> 6;
    const int wm = wave >> 1, wn = wave & 1, lr = lane & 15, lc = lane >> 4;
#pragma unroll
    for (int mi = 0; mi < 4; mi++)
#pragma unroll
        for (int nj = 0; nj < 4; nj++)
#pragma unroll
            for (int i = 0; i < 4; i++) {
                int row = brow + wm * 64 + mi * 16 + lc * 4 + i;
                int col = bcol + wn * 64 + nj * 16 + lr;
                float val = (acc[mi][nj][i] + bias[col]) * scale;
                ushort h = f2bf(val);
                Oh[(size_t)row * D_ + col] = h;
                if (Ol) Ol[(size_t)row * D_ + col] = f2bf(val - bf2f(h));
            }
}

// ---- GEMM variant: output-projection + emask combine (out += s*(acc+bias)) ----
__global__ __launch_bounds__(256, 2) void gemm_combine(
    const ushort* __restrict__ A0, const ushort* __restrict__ A1,
    const ushort* __restrict__ B0, const ushort* __restrict__ B1,
    const float* __restrict__ bias, const float* __restrict__ emask, int e,
    float* __restrict__ out, int K)
{
    __shared__ ushort lds[16384];
    floatv4 acc[4][4];
#pragma unroll
    for (int i = 0; i < 4; i++)
#pragma unroll
        for (int j = 0; j < 4; j++)
#pragma unroll
            for (int q = 0; q < 4; q++) acc[i][j][q] = 0.f;

    const int brow = blockIdx.y * 128, bcol = blockIdx.x * 128;
    gemm_core(A0, A1, B0, B1, K, brow, bcol, lds, acc);

    const int lane = threadIdx.x & 63, wave = threadIdx.x >> 6;
    const int wm = wave >> 1, wn = wave & 1, lr = lane & 15, lc = lane >> 4;
#pragma unroll
    for (int mi = 0; mi < 4; mi++)
#pragma unroll
        for (int nj = 0; nj < 4; nj++)
#pragma unroll
            for (int i = 0; i < 4; i++) {
                int row = brow + wm * 64 + mi * 16 + lc * 4 + i;
                float s = emask[(size_t)row * E_ + e];
                if (s != 0.f) {
                    int col = bcol + wn * 64 + nj * 16 + lr;
                    out[(size_t)row * D_ + col] += s * (acc[mi][nj][i] + bias[col]);
                }
            }
}

// ---------------------------------------------------------------------------
// MFMA flash attention, one expert. grid (S/64, B*H), 256 thr = 4 waves.
// Wave w: 16 q-rows. K-tiles of 64. Q,K split-bf16 (3-term QK^T); P,V bf16.
// K staged via global_load_lds with chunk swizzle c^(r&7); V reg-staged
// transposed into padded rows; P per-wave in padded LDS.
// ---------------------------------------------------------------------------
__global__ __launch_bounds__(256, 2) void attn_mfma(
    const ushort* __restrict__ qh, const ushort* __restrict__ ql,
    const ushort* __restrict__ kh, const ushort* __restrict__ kl,
    const ushort* __restrict__ vv,
    ushort* __restrict__ oh, ushort* __restrict__ ol)
{
    __shared__ ushort Kh[4096], Kl[4096];   // [64][64] bf16, 128B rows, swizzled
    __shared__ ushort Vt[64 * 72];          // [d=64][k=64+pad8]
    __shared__ ushort Pw[4][16 * 72];       // per-wave P [16 q][64 k + pad8]

    const int tid = threadIdx.x;
    const int wave = tid >> 6, lane = tid & 63;
    const int lr = lane & 15, lc = lane >> 4;
    const int bhid = blockIdx.y, bb = bhid >> 4, hh = bhid & 15;
    const int q0 = blockIdx.x * 64;
    const size_t rowbase = (size_t)bb * S_ * D_ + hh * 64;

    shortv8 qfh[2], qfl[2];
    {
        size_t qoff = rowbase + (size_t)(q0 + wave * 16 + lr) * D_ + lc * 8;
        qfh[0] = *(const shortv8*)(qh + qoff);
        qfh[1] = *(const shortv8*)(qh + qoff + 32);
        qfl[0] = *(const shortv8*)(ql + qoff);
        qfl[1] = *(const shortv8*)(ql + qoff + 32);
    }

    floatv4 ov[4];
    float m4[4], l4[4];
#pragma unroll
    for (int df = 0; df < 4; df++)
#pragma unroll
        for (int i = 0; i < 4; i++) ov[df][i] = 0.f;
#pragma unroll
    for (int i = 0; i < 4; i++) { m4[i] = -3.0e38f; l4[i] = 0.f; }

    for (int kt = 0; kt < S_ / 64; kt++) {
        const int kk0 = kt * 64;
        __syncthreads();   // prev tile's PV reads of Vt done

        // stage K hi/lo (swizzled source, linear LDS dest)
#pragma unroll
        for (int t = 0; t < 2; t++) {
            const ushort* src = t ? kl : kh;
            ushort* dst = t ? Kl : Kh;
#pragma unroll
            for (int s = 0; s < 2; s++) {
                int p = s * 256 + tid;
                int r = p >> 3;
                int c = (p & 7) ^ (r & 7);
                gload16(src + rowbase + (size_t)(kk0 + r) * D_ + c * 8, dst + p * 8);
            }
        }
        // stage V transposed: wave handles d-chunk wave*16..+15, lane = k
        {
            const ushort* vsrc = vv + rowbase + (size_t)(kk0 + lane) * D_ + wave * 16;
            ushortv8 v0 = *(const ushortv8*)vsrc;
            ushortv8 v1 = *(const ushortv8*)(vsrc + 8);
#pragma unroll
            for (int j = 0; j < 8; j++) Vt[(wave * 16 + j) * 72 + lane] = v0[j];
#pragma unroll
            for (int j = 0; j < 8; j++) Vt[(wave * 16 + 8 + j) * 72 + lane] = v1[j];
        }
        __syncthreads();

        // QK^T: scores 16q x 64k per wave (pre-scaled by 1/8 via Q)
        floatv4 sc[4];
#pragma unroll
        for (int n = 0; n < 4; n++)
#pragma unroll
            for (int i = 0; i < 4; i++) sc[n][i] = 0.f;
#pragma unroll
        for (int n = 0; n < 4; n++)
#pragma unroll
            for (int ds = 0; ds < 2; ds++) {
                int off = (16 * n + lr) * 64 + (((ds * 4 + lc) ^ (lr & 7)) * 8);
                shortv8 kfh = *(const shortv8*)(Kh + off);
                shortv8 kfl = *(const shortv8*)(Kl + off);
                sc[n] = __builtin_amdgcn_mfma_f32_16x16x32_bf16(qfh[ds], kfh, sc[n], 0, 0, 0);
                sc[n] = __builtin_amdgcn_mfma_f32_16x16x32_bf16(qfh[ds], kfl, sc[n], 0, 0, 0);
                sc[n] = __builtin_amdgcn_mfma_f32_16x16x32_bf16(qfl[ds], kfh, sc[n], 0, 0, 0);
            }

        // online softmax (state per lane for q = 4*lc + i, replicated over lr)
        float tm[4];
#pragma unroll
        for (int i = 0; i < 4; i++)
            tm[i] = fmaxf(fmaxf(sc[0][i], sc[1][i]), fmaxf(sc[2][i], sc[3][i]));
#pragma unroll
        for (int off = 1; off <= 8; off <<= 1)
#pragma unroll
            for (int i = 0; i < 4; i++)
                tm[i] = fmaxf(tm[i], __shfl_xor(tm[i], off));

        float nm[4], sca[4], ps[4];
#pragma unroll
        for (int i = 0; i < 4; i++) {
            nm[i] = fmaxf(m4[i], tm[i]);
            sca[i] = __expf(m4[i] - nm[i]);
            ps[i] = 0.f;
        }
        float pval[4][4];
#pragma unroll
        for (int n = 0; n < 4; n++)
#pragma unroll
            for (int i = 0; i < 4; i++) {
                float p = __expf(sc[n][i] - nm[i]);
                pval[n][i] = p;
                ps[i] += p;
            }
#pragma unroll
        for (int off = 1; off <= 8; off <<= 1)
#pragma unroll
            for (int i = 0; i < 4; i++)
                ps[i] += __shfl_xor(ps[i], off);
#pragma unroll
        for (int i = 0; i < 4; i++) {
            l4[i] = l4[i] * sca[i] + ps[i];
            m4[i] = nm[i];
        }
#pragma unroll
        for (int df = 0; df < 4; df++)
#pragma unroll
            for (int i = 0; i < 4; i++) ov[df][i] *= sca[i];

        // P -> LDS (bf16), then PV
#pragma unroll
        for (int n = 0; n < 4; n++)
#pragma unroll
            for (int i = 0; i < 4; i++)
                Pw[wave][(lc * 4 + i) * 72 + 16 * n + lr] = f2bf(pval[n][i]);
        __syncthreads();

#pragma unroll
        for (int ks = 0; ks < 2; ks++) {
            shortv8 pa = *(const shortv8*)(&Pw[wave][lr * 72 + ks * 32 + lc * 8]);
#pragma unroll
            for (int df = 0; df < 4; df++) {
                shortv8 vf = *(const shortv8*)(Vt + (df * 16 + lr) * 72 + ks * 32 + lc * 8);
                ov[df] = __builtin_amdgcn_mfma_f32_16x16x32_bf16(pa, vf, ov[df], 0, 0, 0);
            }
        }
    }

    // epilogue: normalize, split-bf16 to o_hi/o_lo
#pragma unroll
    for (int df = 0; df < 4; df++)
#pragma unroll
        for (int i = 0; i < 4; i++) {
            float val = ov[df][i] / l4[i];
            size_t off = rowbase + (size_t)(q0 + wave * 16 + lc * 4 + i) * D_ + df * 16 + lr;
            ushort h, l;
            splitbf(val, h, l);
            oh[off] = h;
            ol[off] = l;
        }
}

// ---------------------------------------------------------------------------
// Elementwise split of x into bf16 hi/lo
// ---------------------------------------------------------------------------
__global__ __launch_bounds__(256) void split_f32(
    const float* __restrict__ in, ushort* __restrict__ hi, ushort* __restrict__ lo)
{
    int i = blockIdx.x * 256 + threadIdx.x;
    float4 v = ((const float4*)in)[i];
    ushortv4 hv, lv;
    ushort h, l;
    splitbf(v.x, h, l); hv[0] = h; lv[0] = l;
    splitbf(v.y, h, l); hv[1] = h; lv[1] = l;
    splitbf(v.z, h, l); hv[2] = h; lv[2] = l;
    splitbf(v.w, h, l); hv[3] = h; lv[3] = l;
    ((ushortv4*)hi)[i] = hv;
    ((ushortv4*)lo)[i] = lv;
}

// ---------------------------------------------------------------------------
// Transpose + split: W[K][N] fp32 -> Th/Tl[N][K] bf16. 64x64 tiles.
// ---------------------------------------------------------------------------
__device__ __forceinline__ void tsplit_body(
    const float* __restrict__ W, ushort* __restrict__ Th, ushort* __restrict__ Tl,
    int K, int N, int n0, int k0)
{
    __shared__ float tile[64][65];
    const int tid = threadIdx.x;
#pragma unroll
    for (int i = 0; i < 16; i++) {
        int idx = i * 256 + tid;
        int r = idx >> 6, c = idx & 63;
        tile[r][c] = W[(size_t)(k0 + r) * N + n0 + c];
    }
    __syncthreads();
#pragma unroll
    for (int i = 0; i < 16; i++) {
        int idx = i * 256 + tid;
        int rn = idx >> 6, ck = idx & 63;
        float v = tile[ck][rn];
        ushort h, l;
        splitbf(v, h, l);
        Th[(size_t)(n0 + rn) * K + k0 + ck] = h;
        Tl[(size_t)(n0 + rn) * K + k0 + ck] = l;
    }
}

__global__ __launch_bounds__(256) void tsplit(
    const float* __restrict__ W, ushort* __restrict__ Th, ushort* __restrict__ Tl,
    int K, int N)
{
    tsplit_body(W, Th, Tl, K, N, blockIdx.x * 64, blockIdx.y * 64);
}

__global__ __launch_bounds__(256) void tsplit4(
    const float* __restrict__ W0, const float* __restrict__ W1,
    const float* __restrict__ W2, const float* __restrict__ W3,
    ushort* __restrict__ Th, ushort* __restrict__ Tl)
{
    const int z = blockIdx.z;
    const float* W = (z == 0) ? W0 : (z == 1) ? W1 : (z == 2) ? W2 : W3;
    tsplit_body(W, Th + (size_t)z * D_ * D_, Tl + (size_t)z * D_ * D_,
                D_, D_, blockIdx.x * 64, blockIdx.y * 64);
}

// ---------------------------------------------------------------------------
// Router post (unchanged from working round-1 version)
// ---------------------------------------------------------------------------
__global__ __launch_bounds__(256) void router_post(
    const float* __restrict__ h,
    const float* __restrict__ ln_g, const float* __restrict__ ln_b,
    const float* __restrict__ Wr2, const float* __restrict__ br2,
    float* __restrict__ emask)
{
    const int t = blockIdx.x;
    const int tid = threadIdx.x;
    __shared__ float red[256];
    __shared__ float logits[E_];

    const float* hr = h + (size_t)t * D2_;
    float x0 = hr[tid], x1 = hr[tid + 256];

    red[tid] = x0 + x1; __syncthreads();
    for (int off = 128; off; off >>= 1) { if (tid < off) red[tid] += red[tid + off]; __syncthreads(); }
    float mu = red[0] * (1.f / 512.f);
    __syncthreads();

    float d0 = x0 - mu, d1 = x1 - mu;
    red[tid] = d0 * d0 + d1 * d1; __syncthreads();
    for (int off = 128; off; off >>= 1) { if (tid < off) red[tid] += red[tid + off]; __syncthreads(); }
    float rs = rsqrtf(red[0] * (1.f / 512.f) + 1e-5f);
    __syncthreads();

    float n0 = fmaxf(fmaf(d0 * rs, ln_g[tid],       ln_b[tid]),       0.f);
    float n1 = fmaxf(fmaf(d1 * rs, ln_g[tid + 256], ln_b[tid + 256]), 0.f);

    for (int e = 0; e < E_; e++) {
        red[tid] = n0 * Wr2[(size_t)tid * E_ + e] + n1 * Wr2[(size_t)(tid + 256) * E_ + e];
        __syncthreads();
        for (int off = 128; off; off >>= 1) { if (tid < off) red[tid] += red[tid + off]; __syncthreads(); }
        if (tid == 0) logits[e] = red[0] + br2[e];
        __syncthreads();
    }

    if (tid == 0) {
        float mx = fmaxf(fmaxf(logits[0], logits[1]), fmaxf(logits[2], logits[3]));
        float p[E_], sum = 0.f;
        for (int e = 0; e < E_; e++) { p[e] = expf(logits[e] - mx); sum += p[e]; }
        float inv = 1.f / sum;
        for (int e = 0; e < E_; e++) p[e] *= inv;
        int i1 = 0;
        for (int e = 1; e < E_; e++) if (p[e] > p[i1]) i1 = e;
        int i2 = -1;
        for (int e = 0; e < E_; e++) { if (e == i1) continue; if (i2 < 0 || p[e] > p[i2]) i2 = e; }
        float o[E_] = {0.f, 0.f, 0.f, 0.f};
        o[i1] = p[i1]; o[i2] = p[i2];
        for (int e = 0; e < E_; e++) emask[(size_t)t * E_ + e] = o[e];
    }
}

// ---------------------------------------------------------------------------
extern "C" void kernel_launch(void* const* d_in, const int* in_sizes, int n_in,
                              void* d_out, int out_size, void* d_ws, size_t ws_size,
                              hipStream_t stream) {
    const float* x   = (const float*)d_in[0];
    const float* Wq  = (const float*)d_in[1];
    const float* bq  = (const float*)d_in[2];
    const float* Wk  = (const float*)d_in[3];
    const float* bk  = (const float*)d_in[4];
    const float* Wv  = (const float*)d_in[5];
    const float* bv  = (const float*)d_in[6];
    const float* Wo  = (const float*)d_in[7];
    const float* bo  = (const float*)d_in[8];
    const float* Wr1 = (const float*)d_in[9];
    const float* br1 = (const float*)d_in[10];
    const float* lng = (const float*)d_in[11];
    const float* lnb = (const float*)d_in[12];
    const float* Wr2 = (const float*)d_in[13];
    const float* br2 = (const float*)d_in[14];

    float* out = (float*)d_out;
    char* w = (char*)d_ws;

    ushort* xh   = (ushort*)w; w += (size_t)NTOK * D_ * 2;       // 4 MB
    ushort* xl   = (ushort*)w; w += (size_t)NTOK * D_ * 2;
    ushort* wr1h = (ushort*)w; w += (size_t)D2_ * D_ * 2;        // 1 MB
    ushort* wr1l = (ushort*)w; w += (size_t)D2_ * D_ * 2;
    ushort* wth  = (ushort*)w; w += (size_t)4 * D_ * D_ * 2;     // 8 MB
    ushort* wtl  = (ushort*)w; w += (size_t)4 * D_ * D_ * 2;
    float*  hbuf = (float*)w;  w += (size_t)NTOK * D2_ * 4;      // 4 MB
    float*  emask= (float*)w;  w += (size_t)NTOK * E_ * 4;
    ushort* qhb  = (ushort*)w; w += (size_t)NTOK * D_ * 2;
    ushort* qlb  = (ushort*)w; w += (size_t)NTOK * D_ * 2;
    ushort* khb  = (ushort*)w; w += (size_t)NTOK * D_ * 2;
    ushort* klb  = (ushort*)w; w += (size_t)NTOK * D_ * 2;
    ushort* vb   = (ushort*)w; w += (size_t)NTOK * D_ * 2;
    ushort* ohb  = (ushort*)w; w += (size_t)NTOK * D_ * 2;
    ushort* olb  = (ushort*)w; w += (size_t)NTOK * D_ * 2;

    hipMemsetAsync(d_out, 0, (size_t)NTOK * D_ * sizeof(float), stream);

    dim3 blk(256);

    split_f32<<<dim3(NTOK * D_ / 1024), blk, 0, stream>>>(x, xh, xl);
    tsplit<<<dim3(D2_ / 64, D_ / 64), blk, 0, stream>>>(Wr1, wr1h, wr1l, D_, D2_);
    gemm_f32<<<dim3(D2_ / 128, NTOK / 128), blk, 0, stream>>>(
        xh, xl, wr1h, wr1l, br1, hbuf, D2_, D_);
    router_post<<<dim3(NTOK), blk, 0, stream>>>(hbuf, lng, lnb, Wr2, br2, emask);

    for (int e = 0; e < E_; e++) {
        const size_t WW = (size_t)D_ * D_;
        tsplit4<<<dim3(16, 16, 4), blk, 0, stream>>>(
            Wq + e * WW, Wk + e * WW, Wv + e * WW, Wo + e * WW, wth, wtl);
        gemm_qkv<<<dim3(D_ / 128, NTOK / 128, 3), blk, 0, stream>>>(
            xh, xl, wth, wtl, bq + (size_t)e * D_, bk + (size_t)e * D_, bv + (size_t)e * D_,
            qhb, qlb, khb, klb, vb, D_);
        attn_mfma<<<dim3(S_ / 64, B_ * H_), blk, 0, stream>>>(
            qhb, qlb, khb, klb, vb, ohb, olb);
        gemm_combine<<<dim3(D_ / 128, NTOK / 128), blk, 0, stream>>>(
            ohb, olb, wth + 3 * WW, wtl + 3 * WW,
            bo + (size_t)e * D_, emask, e, out, D_);
    }
}

// Round 3
// 359.551 us; speedup vs baseline: 7.9823x; 1.6694x over previous
//
#include <hip/hip_runtime.h>
#include <hip/hip_bf16.h>
#include <math.h>

#define B_   4
#define S_   512
#define D_   1024
#define H_   16
#define E_   4
#define HD_  64
#define D2_  512
#define NTOK (B_*S_)   // 2048

#define TDE ((size_t)NTOK * D_)   // elements of one [NTOK,D] buffer
#define WWE ((size_t)D_ * D_)     // elements of one [D,D] weight
#define ND2 ((size_t)NTOK * D2_)

typedef unsigned short ushort;
typedef short shortv8 __attribute__((ext_vector_type(8)));
typedef ushort ushortv8 __attribute__((ext_vector_type(8)));
typedef ushort ushortv4 __attribute__((ext_vector_type(4)));
typedef float floatv4 __attribute__((ext_vector_type(4)));

__device__ __forceinline__ ushort f2bf(float f) {
    union { __hip_bfloat16 b; ushort u; } cv;
    cv.b = __float2bfloat16(f);
    return cv.u;
}
__device__ __forceinline__ float bf2f(ushort u) {
    union { ushort u; __hip_bfloat16 b; } cv;
    cv.u = u;
    return __bfloat162float(cv.b);
}
__device__ __forceinline__ void splitbf(float v, ushort& hi, ushort& lo) {
    hi = f2bf(v);
    lo = f2bf(v - bf2f(hi));
}
__device__ __forceinline__ void gload16(const ushort* g, ushort* l) {
    __builtin_amdgcn_global_load_lds(
        (const __attribute__((address_space(1))) unsigned int*)g,
        (__attribute__((address_space(3))) unsigned int*)l, 16, 0, 0);
}

// ---------------------------------------------------------------------------
// Split-bf16 GEMM core (validated round 2): C = A @ Wt^T, A=[M][Kstride] hi/lo,
// Wt=[N][Kstride] hi/lo. 128x128 tile, BK=32, 4 waves, 4x4 frag 16x16x32.
// 3-term split. klen <= Kstride allows split-K callers (pointers pre-offset).
// ---------------------------------------------------------------------------
__device__ __forceinline__ void gemm_core(
    const ushort* __restrict__ A0, const ushort* __restrict__ A1,
    const ushort* __restrict__ B0, const ushort* __restrict__ B1,
    int K, int klen, int brow, int bcol, ushort* lds, floatv4 acc[4][4])
{
    const int tid  = threadIdx.x;
    const int wave = tid >> 6, lane = tid & 63;
    const int wm = wave >> 1, wn = wave & 1;
    const int lr = lane & 15, lc = lane >> 4;

    const ushort* gsrc[4] = {A0, A1, B0, B1};
    size_t  goff[4][2];
    ushort* ldst[4][2];
#pragma unroll
    for (int t = 0; t < 4; t++) {
        int rb = (t < 2) ? brow : bcol;
#pragma unroll
        for (int s = 0; s < 2; s++) {
            int p = s * 256 + tid;
            int m = p >> 2;
            int c = (p & 3) ^ ((m >> 1) & 3);
            goff[t][s] = (size_t)(rb + m) * K + c * 8;
            ldst[t][s] = lds + t * 4096 + p * 8;
        }
    }

    int aoff[4], boff[4];
#pragma unroll
    for (int i = 0; i < 4; i++) {
        int ra = wm * 64 + i * 16 + lr;
        aoff[i] = ra * 32 + ((lc ^ ((ra >> 1) & 3)) * 8);
        int rb2 = wn * 64 + i * 16 + lr;
        boff[i] = rb2 * 32 + ((lc ^ ((rb2 >> 1) & 3)) * 8);
    }

    for (int k0 = 0; k0 < klen; k0 += 32) {
        __syncthreads();
#pragma unroll
        for (int t = 0; t < 4; t++)
#pragma unroll
            for (int s = 0; s < 2; s++)
                gload16(gsrc[t] + goff[t][s] + k0, ldst[t][s]);
        __syncthreads();

        shortv8 ah[4], al[4], bh[4], bl[4];
#pragma unroll
        for (int i = 0; i < 4; i++) {
            ah[i] = *(const shortv8*)(lds +         aoff[i]);
            al[i] = *(const shortv8*)(lds +  4096 + aoff[i]);
            bh[i] = *(const shortv8*)(lds +  8192 + boff[i]);
            bl[i] = *(const shortv8*)(lds + 12288 + boff[i]);
        }
#pragma unroll
        for (int mi = 0; mi < 4; mi++)
#pragma unroll
            for (int nj = 0; nj < 4; nj++) {
                acc[mi][nj] = __builtin_amdgcn_mfma_f32_16x16x32_bf16(ah[mi], bh[nj], acc[mi][nj], 0, 0, 0);
                acc[mi][nj] = __builtin_amdgcn_mfma_f32_16x16x32_bf16(ah[mi], bl[nj], acc[mi][nj], 0, 0, 0);
                acc[mi][nj] = __builtin_amdgcn_mfma_f32_16x16x32_bf16(al[mi], bh[nj], acc[mi][nj], 0, 0, 0);
            }
    }
}

#define ACC_INIT(acc) \
    _Pragma("unroll") for (int i = 0; i < 4; i++) \
    _Pragma("unroll") for (int j = 0; j < 4; j++) \
    _Pragma("unroll") for (int q = 0; q < 4; q++) acc[i][j][q] = 0.f;

// ---- Router hidden GEMM, split-K x4 across z: hpart[z] = x@Wr1 (K chunk) ----
__global__ __launch_bounds__(256, 2) void gemm_router(
    const ushort* __restrict__ xh, const ushort* __restrict__ xl,
    const ushort* __restrict__ wr1h, const ushort* __restrict__ wr1l,
    float* __restrict__ hpart)
{
    __shared__ ushort lds[16384];
    floatv4 acc[4][4];
    ACC_INIT(acc)

    const int kz = blockIdx.z;              // K chunk of 256
    const int koff = kz * 256;
    const int brow = blockIdx.y * 128, bcol = blockIdx.x * 128;
    gemm_core(xh + koff, xl + koff, wr1h + koff, wr1l + koff,
              D_, 256, brow, bcol, lds, acc);

    float* C = hpart + (size_t)kz * ND2;
    const int lane = threadIdx.x & 63, wave = threadIdx.x >> 6;
    const int wm = wave >> 1, wn = wave & 1, lr = lane & 15, lc = lane >> 4;
#pragma unroll
    for (int mi = 0; mi < 4; mi++)
#pragma unroll
        for (int nj = 0; nj < 4; nj++)
#pragma unroll
            for (int i = 0; i < 4; i++) {
                int row = brow + wm * 64 + mi * 16 + lc * 4 + i;
                int col = bcol + wn * 64 + nj * 16 + lr;
                C[(size_t)row * D2_ + col] = acc[mi][nj][i];
            }
}

// ---- Fused Q/K/V projections for nslots experts: z = slot*3 + m ----
__global__ __launch_bounds__(256, 2) void gemm_qkv_all(
    const ushort* __restrict__ xh, const ushort* __restrict__ xl,
    const ushort* __restrict__ wth, const ushort* __restrict__ wtl,
    const float* __restrict__ bq, const float* __restrict__ bk, const float* __restrict__ bv,
    ushort* __restrict__ qh, ushort* __restrict__ ql,
    ushort* __restrict__ kh, ushort* __restrict__ kl,
    ushort* __restrict__ vb, int ebase)
{
    __shared__ ushort lds[16384];
    const int slot = blockIdx.z / 3, m = blockIdx.z % 3;
    const int e = ebase + slot;
    const size_t so = (size_t)slot * TDE;
    const ushort* B0 = wth + (size_t)(slot * 4 + m) * WWE;
    const ushort* B1 = wtl + (size_t)(slot * 4 + m) * WWE;
    const float* bias = ((m == 0) ? bq : (m == 1) ? bk : bv) + (size_t)e * D_;
    ushort* Oh = ((m == 0) ? qh : (m == 1) ? kh : vb) + so;
    ushort* Ol = (m == 0) ? ql + so : (m == 1) ? kl + so : nullptr;
    const float scale = (m == 0) ? 0.125f : 1.0f;

    floatv4 acc[4][4];
    ACC_INIT(acc)

    const int brow = blockIdx.y * 128, bcol = blockIdx.x * 128;
    gemm_core(xh, xl, B0, B1, D_, D_, brow, bcol, lds, acc);

    const int lane = threadIdx.x & 63, wave = threadIdx.x >> 6;
    const int wm = wave >> 1, wn = wave & 1, lr = lane & 15, lc = lane >> 4;
#pragma unroll
    for (int mi = 0; mi < 4; mi++)
#pragma unroll
        for (int nj = 0; nj < 4; nj++)
#pragma unroll
            for (int i = 0; i < 4; i++) {
                int row = brow + wm * 64 + mi * 16 + lc * 4 + i;
                int col = bcol + wn * 64 + nj * 16 + lr;
                float val = (acc[mi][nj][i] + bias[col]) * scale;
                ushort h = f2bf(val);
                Oh[(size_t)row * D_ + col] = h;
                if (Ol) Ol[(size_t)row * D_ + col] = f2bf(val - bf2f(h));
            }
}

// ---- Output projection + mask: fused (write out4 slice) or fallback (+= out)
__global__ __launch_bounds__(256, 2) void gemm_combine4(
    const ushort* __restrict__ oh, const ushort* __restrict__ ol,
    const ushort* __restrict__ wth, const ushort* __restrict__ wtl,
    const float* __restrict__ bo, const float* __restrict__ emask,
    float* __restrict__ out, float* __restrict__ out4, int ebase, int fused)
{
    __shared__ ushort lds[16384];
    const int slot = blockIdx.z;
    const int e = ebase + slot;
    const size_t so = (size_t)slot * TDE;
    const ushort* A0 = oh + so;
    const ushort* A1 = ol + so;
    const ushort* B0 = wth + (size_t)(slot * 4 + 3) * WWE;
    const ushort* B1 = wtl + (size_t)(slot * 4 + 3) * WWE;
    const float* bias = bo + (size_t)e * D_;

    floatv4 acc[4][4];
    ACC_INIT(acc)

    const int brow = blockIdx.y * 128, bcol = blockIdx.x * 128;
    gemm_core(A0, A1, B0, B1, D_, D_, brow, bcol, lds, acc);

    float* dst = fused ? (out4 + so) : out;
    const int lane = threadIdx.x & 63, wave = threadIdx.x >> 6;
    const int wm = wave >> 1, wn = wave & 1, lr = lane & 15, lc = lane >> 4;
#pragma unroll
    for (int mi = 0; mi < 4; mi++)
#pragma unroll
        for (int nj = 0; nj < 4; nj++)
#pragma unroll
            for (int i = 0; i < 4; i++) {
                int row = brow + wm * 64 + mi * 16 + lc * 4 + i;
                float s = emask[(size_t)row * E_ + e];
                if (s != 0.f) {
                    int col = bcol + wn * 64 + nj * 16 + lr;
                    float v = s * (acc[mi][nj][i] + bias[col]);
                    if (fused) dst[(size_t)row * D_ + col] = v;
                    else       dst[(size_t)row * D_ + col] += v;
                }
            }
}

// ---- reduce out4 slices -> out ----
__global__ __launch_bounds__(256) void reduce_out(
    const float* __restrict__ out4, float* __restrict__ out)
{
    size_t i = (size_t)blockIdx.x * 256 + threadIdx.x;
    const float4* p = (const float4*)out4;
    float4 a = p[i], b = p[i + TDE / 4], c = p[i + 2 * (TDE / 4)], d = p[i + 3 * (TDE / 4)];
    float4 r;
    r.x = a.x + b.x + c.x + d.x;
    r.y = a.y + b.y + c.y + d.y;
    r.z = a.z + b.z + c.z + d.z;
    r.w = a.w + b.w + c.w + d.w;
    ((float4*)out)[i] = r;
}

// ---------------------------------------------------------------------------
// MFMA flash attention (validated round 2), nslots experts via blockIdx.z.
// ---------------------------------------------------------------------------
__global__ __launch_bounds__(256, 2) void attn_all(
    const ushort* __restrict__ qh_, const ushort* __restrict__ ql_,
    const ushort* __restrict__ kh_, const ushort* __restrict__ kl_,
    const ushort* __restrict__ vv_,
    ushort* __restrict__ oh_, ushort* __restrict__ ol_)
{
    __shared__ ushort Kh[4096], Kl[4096];   // [64][64] bf16, swizzled
    __shared__ ushort Vt[64 * 72];          // [d][k+pad]
    __shared__ ushort Pw[4][16 * 72];       // per-wave P

    const size_t zo = (size_t)blockIdx.z * TDE;
    const ushort* qh = qh_ + zo; const ushort* ql = ql_ + zo;
    const ushort* kh = kh_ + zo; const ushort* kl = kl_ + zo;
    const ushort* vv = vv_ + zo;
    ushort* oh = oh_ + zo; ushort* ol = ol_ + zo;

    const int tid = threadIdx.x;
    const int wave = tid >> 6, lane = tid & 63;
    const int lr = lane & 15, lc = lane >> 4;
    const int bhid = blockIdx.y, bb = bhid >> 4, hh = bhid & 15;
    const int q0 = blockIdx.x * 64;
    const size_t rowbase = (size_t)bb * S_ * D_ + hh * 64;

    shortv8 qfh[2], qfl[2];
    {
        size_t qoff = rowbase + (size_t)(q0 + wave * 16 + lr) * D_ + lc * 8;
        qfh[0] = *(const shortv8*)(qh + qoff);
        qfh[1] = *(const shortv8*)(qh + qoff + 32);
        qfl[0] = *(const shortv8*)(ql + qoff);
        qfl[1] = *(const shortv8*)(ql + qoff + 32);
    }

    floatv4 ov[4];
    float m4[4], l4[4];
#pragma unroll
    for (int df = 0; df < 4; df++)
#pragma unroll
        for (int i = 0; i < 4; i++) ov[df][i] = 0.f;
#pragma unroll
    for (int i = 0; i < 4; i++) { m4[i] = -3.0e38f; l4[i] = 0.f; }

    for (int kt = 0; kt < S_ / 64; kt++) {
        const int kk0 = kt * 64;
        __syncthreads();

#pragma unroll
        for (int t = 0; t < 2; t++) {
            const ushort* src = t ? kl : kh;
            ushort* dst = t ? Kl : Kh;
#pragma unroll
            for (int s = 0; s < 2; s++) {
                int p = s * 256 + tid;
                int r = p >> 3;
                int c = (p & 7) ^ (r & 7);
                gload16(src + rowbase + (size_t)(kk0 + r) * D_ + c * 8, dst + p * 8);
            }
        }
        {
            const ushort* vsrc = vv + rowbase + (size_t)(kk0 + lane) * D_ + wave * 16;
            ushortv8 v0 = *(const ushortv8*)vsrc;
            ushortv8 v1 = *(const ushortv8*)(vsrc + 8);
#pragma unroll
            for (int j = 0; j < 8; j++) Vt[(wave * 16 + j) * 72 + lane] = v0[j];
#pragma unroll
            for (int j = 0; j < 8; j++) Vt[(wave * 16 + 8 + j) * 72 + lane] = v1[j];
        }
        __syncthreads();

        floatv4 sc[4];
#pragma unroll
        for (int n = 0; n < 4; n++)
#pragma unroll
            for (int i = 0; i < 4; i++) sc[n][i] = 0.f;
#pragma unroll
        for (int n = 0; n < 4; n++)
#pragma unroll
            for (int ds = 0; ds < 2; ds++) {
                int off = (16 * n + lr) * 64 + (((ds * 4 + lc) ^ (lr & 7)) * 8);
                shortv8 kfh = *(const shortv8*)(Kh + off);
                shortv8 kfl = *(const shortv8*)(Kl + off);
                sc[n] = __builtin_amdgcn_mfma_f32_16x16x32_bf16(qfh[ds], kfh, sc[n], 0, 0, 0);
                sc[n] = __builtin_amdgcn_mfma_f32_16x16x32_bf16(qfh[ds], kfl, sc[n], 0, 0, 0);
                sc[n] = __builtin_amdgcn_mfma_f32_16x16x32_bf16(qfl[ds], kfh, sc[n], 0, 0, 0);
            }

        float tm[4];
#pragma unroll
        for (int i = 0; i < 4; i++)
            tm[i] = fmaxf(fmaxf(sc[0][i], sc[1][i]), fmaxf(sc[2][i], sc[3][i]));
#pragma unroll
        for (int off = 1; off <= 8; off <<= 1)
#pragma unroll
            for (int i = 0; i < 4; i++)
                tm[i] = fmaxf(tm[i], __shfl_xor(tm[i], off));

        float nm[4], sca[4], ps[4];
#pragma unroll
        for (int i = 0; i < 4; i++) {
            nm[i] = fmaxf(m4[i], tm[i]);
            sca[i] = __expf(m4[i] - nm[i]);
            ps[i] = 0.f;
        }
        float pval[4][4];
#pragma unroll
        for (int n = 0; n < 4; n++)
#pragma unroll
            for (int i = 0; i < 4; i++) {
                float p = __expf(sc[n][i] - nm[i]);
                pval[n][i] = p;
                ps[i] += p;
            }
#pragma unroll
        for (int off = 1; off <= 8; off <<= 1)
#pragma unroll
            for (int i = 0; i < 4; i++)
                ps[i] += __shfl_xor(ps[i], off);
#pragma unroll
        for (int i = 0; i < 4; i++) {
            l4[i] = l4[i] * sca[i] + ps[i];
            m4[i] = nm[i];
        }
#pragma unroll
        for (int df = 0; df < 4; df++)
#pragma unroll
            for (int i = 0; i < 4; i++) ov[df][i] *= sca[i];

#pragma unroll
        for (int n = 0; n < 4; n++)
#pragma unroll
            for (int i = 0; i < 4; i++)
                Pw[wave][(lc * 4 + i) * 72 + 16 * n + lr] = f2bf(pval[n][i]);
        __syncthreads();

#pragma unroll
        for (int ks = 0; ks < 2; ks++) {
            shortv8 pa = *(const shortv8*)(&Pw[wave][lr * 72 + ks * 32 + lc * 8]);
#pragma unroll
            for (int df = 0; df < 4; df++) {
                shortv8 vf = *(const shortv8*)(Vt + (df * 16 + lr) * 72 + ks * 32 + lc * 8);
                ov[df] = __builtin_amdgcn_mfma_f32_16x16x32_bf16(pa, vf, ov[df], 0, 0, 0);
            }
        }
    }

#pragma unroll
    for (int df = 0; df < 4; df++)
#pragma unroll
        for (int i = 0; i < 4; i++) {
            float val = ov[df][i] / l4[i];
            size_t off = rowbase + (size_t)(q0 + wave * 16 + lc * 4 + i) * D_ + df * 16 + lr;
            ushort h, l;
            splitbf(val, h, l);
            oh[off] = h;
            ol[off] = l;
        }
}

// ---------------------------------------------------------------------------
__global__ __launch_bounds__(256) void split_f32(
    const float* __restrict__ in, ushort* __restrict__ hi, ushort* __restrict__ lo)
{
    int i = blockIdx.x * 256 + threadIdx.x;
    float4 v = ((const float4*)in)[i];
    ushortv4 hv, lv;
    ushort h, l;
    splitbf(v.x, h, l); hv[0] = h; lv[0] = l;
    splitbf(v.y, h, l); hv[1] = h; lv[1] = l;
    splitbf(v.z, h, l); hv[2] = h; lv[2] = l;
    splitbf(v.w, h, l); hv[3] = h; lv[3] = l;
    ((ushortv4*)hi)[i] = hv;
    ((ushortv4*)lo)[i] = lv;
}

// ---------------------------------------------------------------------------
// Transpose + split: W[K][N] fp32 -> Th/Tl[N][K] bf16. 64x64 tiles.
// ---------------------------------------------------------------------------
__device__ __forceinline__ void tsplit_body(
    const float* __restrict__ W, ushort* __restrict__ Th, ushort* __restrict__ Tl,
    int K, int N, int n0, int k0)
{
    __shared__ float tile[64][65];
    const int tid = threadIdx.x;
#pragma unroll
    for (int i = 0; i < 16; i++) {
        int idx = i * 256 + tid;
        int r = idx >> 6, c = idx & 63;
        tile[r][c] = W[(size_t)(k0 + r) * N + n0 + c];
    }
    __syncthreads();
#pragma unroll
    for (int i = 0; i < 16; i++) {
        int idx = i * 256 + tid;
        int rn = idx >> 6, ck = idx & 63;
        float v = tile[ck][rn];
        ushort h, l;
        splitbf(v, h, l);
        Th[(size_t)(n0 + rn) * K + k0 + ck] = h;
        Tl[(size_t)(n0 + rn) * K + k0 + ck] = l;
    }
}

__global__ __launch_bounds__(256) void tsplit(
    const float* __restrict__ W, ushort* __restrict__ Th, ushort* __restrict__ Tl,
    int K, int N)
{
    tsplit_body(W, Th, Tl, K, N, blockIdx.x * 64, blockIdx.y * 64);
}

// all-expert weight transpose+split: mat = mbase + z, slot-local output
__global__ __launch_bounds__(256) void tsplit16(
    const float* __restrict__ Wq, const float* __restrict__ Wk,
    const float* __restrict__ Wv, const float* __restrict__ Wo,
    ushort* __restrict__ Th, ushort* __restrict__ Tl, int mbase)
{
    const int mg = mbase + blockIdx.z;
    const int e = mg >> 2, m = mg & 3;
    const float* W = ((m == 0) ? Wq : (m == 1) ? Wk : (m == 2) ? Wv : Wo) + (size_t)e * WWE;
    tsplit_body(W, Th + (size_t)blockIdx.z * WWE, Tl + (size_t)blockIdx.z * WWE,
                D_, D_, blockIdx.x * 64, blockIdx.y * 64);
}

// ---------------------------------------------------------------------------
// Router post: sums 4 split-K partials + bias, LN, relu, logits, softmax, top2
// ---------------------------------------------------------------------------
__global__ __launch_bounds__(256) void router_post(
    const float* __restrict__ hpart, const float* __restrict__ br1,
    const float* __restrict__ ln_g, const float* __restrict__ ln_b,
    const float* __restrict__ Wr2, const float* __restrict__ br2,
    float* __restrict__ emask)
{
    const int t = blockIdx.x;
    const int tid = threadIdx.x;
    __shared__ float red[256];
    __shared__ float logits[E_];

    const float* hp = hpart + (size_t)t * D2_;
    float x0 = hp[tid] + hp[ND2 + tid] + hp[2 * ND2 + tid] + hp[3 * ND2 + tid] + br1[tid];
    float x1 = hp[tid + 256] + hp[ND2 + tid + 256] + hp[2 * ND2 + tid + 256]
             + hp[3 * ND2 + tid + 256] + br1[tid + 256];

    red[tid] = x0 + x1; __syncthreads();
    for (int off = 128; off; off >>= 1) { if (tid < off) red[tid] += red[tid + off]; __syncthreads(); }
    float mu = red[0] * (1.f / 512.f);
    __syncthreads();

    float d0 = x0 - mu, d1 = x1 - mu;
    red[tid] = d0 * d0 + d1 * d1; __syncthreads();
    for (int off = 128; off; off >>= 1) { if (tid < off) red[tid] += red[tid + off]; __syncthreads(); }
    float rs = rsqrtf(red[0] * (1.f / 512.f) + 1e-5f);
    __syncthreads();

    float n0 = fmaxf(fmaf(d0 * rs, ln_g[tid],       ln_b[tid]),       0.f);
    float n1 = fmaxf(fmaf(d1 * rs, ln_g[tid + 256], ln_b[tid + 256]), 0.f);

    for (int e = 0; e < E_; e++) {
        red[tid] = n0 * Wr2[(size_t)tid * E_ + e] + n1 * Wr2[(size_t)(tid + 256) * E_ + e];
        __syncthreads();
        for (int off = 128; off; off >>= 1) { if (tid < off) red[tid] += red[tid + off]; __syncthreads(); }
        if (tid == 0) logits[e] = red[0] + br2[e];
        __syncthreads();
    }

    if (tid == 0) {
        float mx = fmaxf(fmaxf(logits[0], logits[1]), fmaxf(logits[2], logits[3]));
        float p[E_], sum = 0.f;
        for (int e = 0; e < E_; e++) { p[e] = expf(logits[e] - mx); sum += p[e]; }
        float inv = 1.f / sum;
        for (int e = 0; e < E_; e++) p[e] *= inv;
        int i1 = 0;
        for (int e = 1; e < E_; e++) if (p[e] > p[i1]) i1 = e;
        int i2 = -1;
        for (int e = 0; e < E_; e++) { if (e == i1) continue; if (i2 < 0 || p[e] > p[i2]) i2 = e; }
        float o[E_] = {0.f, 0.f, 0.f, 0.f};
        o[i1] = p[i1]; o[i2] = p[i2];
        for (int e = 0; e < E_; e++) emask[(size_t)t * E_ + e] = o[e];
    }
}

// ---------------------------------------------------------------------------
extern "C" void kernel_launch(void* const* d_in, const int* in_sizes, int n_in,
                              void* d_out, int out_size, void* d_ws, size_t ws_size,
                              hipStream_t stream) {
    const float* x   = (const float*)d_in[0];
    const float* Wq  = (const float*)d_in[1];
    const float* bq  = (const float*)d_in[2];
    const float* Wk  = (const float*)d_in[3];
    const float* bk  = (const float*)d_in[4];
    const float* Wv  = (const float*)d_in[5];
    const float* bv  = (const float*)d_in[6];
    const float* Wo  = (const float*)d_in[7];
    const float* bo  = (const float*)d_in[8];
    const float* Wr1 = (const float*)d_in[9];
    const float* br1 = (const float*)d_in[10];
    const float* lng = (const float*)d_in[11];
    const float* lnb = (const float*)d_in[12];
    const float* Wr2 = (const float*)d_in[13];
    const float* br2 = (const float*)d_in[14];

    float* out = (float*)d_out;
    char* w = (char*)d_ws;
    dim3 blk(256);

    const size_t MB = 1024ull * 1024ull;
    const size_t need_fused = 185 * MB;

    if (ws_size >= need_fused) {
        // ---------- fully fused path (aliased regions, ~177 MB) ----------
        float*  emask = (float*)w;                       // 32 KB (pad to 64K)
        ushort* wth   = (ushort*)(w + 64 * 1024);        // 32 MB (16 mats)
        ushort* wtl   = (ushort*)(w + 64 * 1024 + 32 * MB);
        char*   AC    = w + 64 * 1024 + 64 * MB;         // 32 MB region
        char*   BD    = AC + 32 * MB;                    // 80 MB region

        // region A (dead after gemm_qkv_all / router_post)
        ushort* xh    = (ushort*)AC;                     // 4 MB
        ushort* xl    = (ushort*)(AC + 4 * MB);
        ushort* wr1h  = (ushort*)(AC + 8 * MB);          // 1 MB
        ushort* wr1l  = (ushort*)(AC + 9 * MB);
        float*  hpart = (float*)(AC + 10 * MB);          // 16 MB
        // region C (born at attn) aliases A
        ushort* ohb   = (ushort*)AC;                     // 16 MB (4 slots)
        ushort* olb   = (ushort*)(AC + 16 * MB);

        // region B (dead after attn)
        ushort* qhb   = (ushort*)BD;                     // 16 MB each
        ushort* qlb   = (ushort*)(BD + 16 * MB);
        ushort* khb   = (ushort*)(BD + 32 * MB);
        ushort* klb   = (ushort*)(BD + 48 * MB);
        ushort* vbb   = (ushort*)(BD + 64 * MB);
        // region D (born after attn) aliases B
        float*  out4  = (float*)BD;                      // 32 MB

        split_f32<<<dim3(NTOK * D_ / 1024), blk, 0, stream>>>(x, xh, xl);
        tsplit<<<dim3(D2_ / 64, D_ / 64), blk, 0, stream>>>(Wr1, wr1h, wr1l, D_, D2_);
        tsplit16<<<dim3(16, 16, 16), blk, 0, stream>>>(Wq, Wk, Wv, Wo, wth, wtl, 0);

        gemm_router<<<dim3(D2_ / 128, NTOK / 128, 4), blk, 0, stream>>>(
            xh, xl, wr1h, wr1l, hpart);
        router_post<<<dim3(NTOK), blk, 0, stream>>>(hpart, br1, lng, lnb, Wr2, br2, emask);

        gemm_qkv_all<<<dim3(D_ / 128, NTOK / 128, 12), blk, 0, stream>>>(
            xh, xl, wth, wtl, bq, bk, bv, qhb, qlb, khb, klb, vbb, 0);
        attn_all<<<dim3(S_ / 64, B_ * H_, 4), blk, 0, stream>>>(
            qhb, qlb, khb, klb, vbb, ohb, olb);

        hipMemsetAsync(out4, 0, 4 * TDE * sizeof(float), stream);
        gemm_combine4<<<dim3(D_ / 128, NTOK / 128, 4), blk, 0, stream>>>(
            ohb, olb, wth, wtl, bo, emask, out, out4, 0, 1);
        reduce_out<<<dim3(TDE / 1024), blk, 0, stream>>>(out4, out);
    } else {
        // ---------- fallback per-expert path (~52 MB) ----------
        float*  emask = (float*)w;
        ushort* xh    = (ushort*)(w + 64 * 1024);
        ushort* xl    = (ushort*)(w + 64 * 1024 + 4 * MB);
        ushort* wth   = (ushort*)(w + 64 * 1024 + 8 * MB);    // 8 MB (4 mats)
        ushort* wtl   = (ushort*)(w + 64 * 1024 + 16 * MB);
        char*   R     = w + 64 * 1024 + 24 * MB;              // 28 MB region
        ushort* wr1h  = (ushort*)R;
        ushort* wr1l  = (ushort*)(R + 1 * MB);
        float*  hpart = (float*)(R + 2 * MB);                 // 16 MB
        ushort* qhb   = (ushort*)R;                           // 4 MB each
        ushort* qlb   = (ushort*)(R + 4 * MB);
        ushort* khb   = (ushort*)(R + 8 * MB);
        ushort* klb   = (ushort*)(R + 12 * MB);
        ushort* vbb   = (ushort*)(R + 16 * MB);
        ushort* ohb   = (ushort*)(R + 20 * MB);
        ushort* olb   = (ushort*)(R + 24 * MB);

        hipMemsetAsync(out, 0, TDE * sizeof(float), stream);

        split_f32<<<dim3(NTOK * D_ / 1024), blk, 0, stream>>>(x, xh, xl);
        tsplit<<<dim3(D2_ / 64, D_ / 64), blk, 0, stream>>>(Wr1, wr1h, wr1l, D_, D2_);
        gemm_router<<<dim3(D2_ / 128, NTOK / 128, 4), blk, 0, stream>>>(
            xh, xl, wr1h, wr1l, hpart);
        router_post<<<dim3(NTOK), blk, 0, stream>>>(hpart, br1, lng, lnb, Wr2, br2, emask);

        for (int e = 0; e < E_; e++) {
            tsplit16<<<dim3(16, 16, 4), blk, 0, stream>>>(Wq, Wk, Wv, Wo, wth, wtl, e * 4);
            gemm_qkv_all<<<dim3(D_ / 128, NTOK / 128, 3), blk, 0, stream>>>(
                xh, xl, wth, wtl, bq, bk, bv, qhb, qlb, khb, klb, vbb, e);
            attn_all<<<dim3(S_ / 64, B_ * H_, 1), blk, 0, stream>>>(
                qhb, qlb, khb, klb, vbb, ohb, olb);
            gemm_combine4<<<dim3(D_ / 128, NTOK / 128, 1), blk, 0, stream>>>(
                ohb, olb, wth, wtl, bo, emask, out, nullptr, e, 0);
        }
    }
}